// Round 8
// baseline (82.488 us; speedup 1.0000x reference)
//
#include <hip/hip_runtime.h>
#include <hip/hip_bf16.h>
#include <math.h>

// ---------------------------------------------------------------------------
// NTXentLoss fused, symmetric triangle, fp8(e4m3) GEMM version.
// loss = mean(lse(logits) - picked), logits = G G^T, G = sqrt(2)*f/||f|| in
// OCP fp8 (2 MB total -> fully L2-resident per XCD). Diagnosis R7: bound was
// staging-transaction volume (8 x 16B lane-requests per MFMA) + 13% occupancy.
// fp8 halves staged bytes AND LDS (2x16KB dbuf = 32KB -> 4 blocks/CU) AND af
// (64 VGPR). 1024 blocks = 32 strip-pairs x 32 splits, XCD-grouped.
// Row-sums -> prow[k] via atomicAdd (2 adds/slot into zeroed mem, order-
// independent); col-sums -> pcol[2rb+wr] writer-unique.
// picked[i<B]=2 exactly; picked[i>=B] fp32 at normalize time.
// ---------------------------------------------------------------------------

#define B_ROWS 4096
#define D_DIM  256
#define N_ROWS 8192
#define NPANEL 64
#define NSPLIT 32

typedef __attribute__((ext_vector_type(4))) float f32x4;

// ---------------- kernel 1: normalize (fp32 -> fp8) + picked ---------------
__global__ __launch_bounds__(256) void nt_norm_picked(
    const float* __restrict__ f1, const float* __restrict__ f2,
    unsigned char* __restrict__ G, float* __restrict__ picked_cross,
    float* __restrict__ prow) {
  __shared__ float4 vbuf[2][64];
  __shared__ float ssbuf[2];
  const int tid = threadIdx.x, lane = tid & 63, w = tid >> 6;
  // zero prow: 32*8192 floats = 65536 float4 (grid 2048 covers)
  const int zidx = blockIdx.x * 256 + tid;
  if (zidx < 65536) reinterpret_cast<float4*>(prow)[zidx] = float4{0.f, 0.f, 0.f, 0.f};
  const int pl = w >> 1, src = w & 1;
  const int p = blockIdx.x * 2 + pl;               // pair index 0..B-1
  const float* rowp = (src == 0 ? f1 : f2) + (size_t)p * D_DIM;
  float4 v = reinterpret_cast<const float4*>(rowp)[lane];
  float ss = v.x * v.x + v.y * v.y + v.z * v.z + v.w * v.w;
#pragma unroll
  for (int m = 1; m < 64; m <<= 1) ss += __shfl_xor(ss, m, 64);
  const float scale = 1.41421356237309515f * rsqrtf(fmaxf(ss, 1e-30f));
  // pack 4 fp8 (OCP e4m3, HW-native cvt)
  int wpk = __builtin_amdgcn_cvt_pk_fp8_f32(v.x * scale, v.y * scale, 0, false);
  wpk     = __builtin_amdgcn_cvt_pk_fp8_f32(v.z * scale, v.w * scale, wpk, true);
  const int grow = p + src * B_ROWS;
  reinterpret_cast<int*>(G + (size_t)grow * D_DIM)[lane] = wpk;
  if (src == 0) { vbuf[pl][lane] = v; if (lane == 0) ssbuf[pl] = ss; }
  __syncthreads();
  if (src == 1) {
    float4 u = vbuf[pl][lane];
    float d = v.x * u.x + v.y * u.y + v.z * u.z + v.w * u.w;
#pragma unroll
    for (int m = 1; m < 64; m <<= 1) d += __shfl_xor(d, m, 64);
    if (lane == 0)
      picked_cross[p] = 2.0f * d * rsqrtf(ss) * rsqrtf(ssbuf[pl]);
  }
}

// ------------- staging: 16KB contiguous global -> LDS, swizzled ------------
// LDS[o] = G[base + swz(o)], swz(o) = o ^ (((o>>8)&7)<<4)  (256B fp8 rows,
// 16B granule -> DMA-compatible involution).
__device__ __forceinline__ void stage_lds(const char* gsrc_base, char* lds_base,
                                          int tid) {
  const int lane = tid & 63, wid = tid >> 6;
#pragma unroll
  for (int r = 0; r < 4; ++r) {
    const int o  = r * 4096 + wid * 1024 + lane * 16;
    const int so = o ^ (((o >> 8) & 7) << 4);
    __builtin_amdgcn_global_load_lds(
        (const __attribute__((address_space(1))) void*)(gsrc_base + so),
        (__attribute__((address_space(3))) void*)(lds_base + r * 4096 + wid * 1024),
        16, 0, 0);
  }
}

// ---------------- A-slice loader: 64 rows x K=256 fp8 -> 64 VGPR -----------
__device__ __forceinline__ void load_af(const char* gb, int rb, int wr,
                                        int l15, int q8, long af[4][8]) {
#pragma unroll
  for (int m = 0; m < 4; ++m) {
    const int ro = (rb * 128 + wr * 64 + m * 16 + l15) * 256;
#pragma unroll
    for (int ks = 0; ks < 8; ++ks)
      af[m][ks] = *reinterpret_cast<const long*>(gb + ro + ks * 32 + q8);
  }
}

// -------- kernel 2: strip-pair fp8 GEMM, wave tile 64x32, fused exp --------
__global__ __launch_bounds__(256, 4) void nt_gemm_tri(
    const unsigned char* __restrict__ G,
    float* __restrict__ prow,   // [NSPLIT][N_ROWS], zero-init'd, atomicAdd
    float* __restrict__ pcol)   // [2*NPANEL][N_ROWS], writer-covered
{
  // XCD-grouped remap: 1024 blocks -> 128 consecutive work items per XCD.
  const int wg  = (blockIdx.x & 7) * 128 + (blockIdx.x >> 3);
  const int p   = wg >> 5;             // pair 0..31: strips rbA=63-p, rbB=p
  const int k   = wg & 31;             // split 0..31
  const int rbA = 63 - p;
  const int n1  = 2 * (rbA + 1);       // subtiles in strip A
  const int t0  = (130 * k) >> 5;
  const int t1  = (130 * (k + 1)) >> 5;

  const int tid = threadIdx.x, lane = tid & 63, wid = tid >> 6;
  const int wr = wid >> 1, wc = wid & 1;     // 64-row half / 32-col half
  const int l15 = lane & 15, q8 = (lane >> 4) << 3;

  __shared__ long lds8[4096];          // 32 KB = 2 x 16 KB B buffers
  char* ldsb = reinterpret_cast<char*>(lds8);
  const char* gb = reinterpret_cast<const char*>(G);

  int rb = (t0 < n1) ? rbA : p;
  stage_lds(gb + (size_t)(t0 < n1 ? t0 : t0 - n1) * 16384, ldsb, tid);

  long af[4][8];                       // 64 rows x K=256 fp8 slice
  load_af(gb, rb, wr, l15, q8, af);

  float rs[16];
#pragma unroll
  for (int i = 0; i < 16; ++i) rs[i] = 0.f;
  __syncthreads();

  for (int t = t0; t < t1; ++t) {
    char* bbuf = ldsb + ((t - t0) & 1) * 16384;
    if (t + 1 < t1) {
      const int sbn = (t + 1 < n1) ? t + 1 : t + 1 - n1;
      stage_lds(gb + (size_t)sbn * 16384, ldsb + ((t + 1 - t0) & 1) * 16384, tid);
    }
    const int sb = (t < n1) ? t : t - n1;

    f32x4 acc[4][2] = {};
#pragma unroll
    for (int ks = 0; ks < 8; ++ks) {
      long bf[2];
#pragma unroll
      for (int n = 0; n < 2; ++n) {
        const int brow = wc * 32 + n * 16 + l15;
        const int off  = (brow * 256 + ks * 32 + q8) ^ ((brow & 7) << 4);
        bf[n] = *reinterpret_cast<const long*>(bbuf + off);
      }
#pragma unroll
      for (int m = 0; m < 4; ++m)
#pragma unroll
        for (int n = 0; n < 2; ++n)
          acc[m][n] = __builtin_amdgcn_mfma_f32_16x16x32_fp8_fp8(
              af[m][ks], bf[n], acc[m][n], 0, 0, 0);
    }

    // exp + sums. acc row = wr*64+m*16+(lane>>4)*4+j, col = sb*64+wc*32+n*16+l15.
    float cs0 = 0.f, cs1 = 0.f;
#pragma unroll
    for (int m = 0; m < 4; ++m)
#pragma unroll
      for (int j = 0; j < 4; ++j) {
        const float e0 = __expf(acc[m][0][j]);
        const float e1 = __expf(acc[m][1][j]);
        rs[m * 4 + j] += e0 + e1;
        cs0 += e0; cs1 += e1;
      }
    if ((sb >> 1) != rb) {             // off-diagonal: store col sums
      cs0 += __shfl_xor(cs0, 16, 64); cs0 += __shfl_xor(cs0, 32, 64);
      cs1 += __shfl_xor(cs1, 16, 64); cs1 += __shfl_xor(cs1, 32, 64);
      if (lane < 16) {
        float* dst = pcol + (size_t)(2 * rb + wr) * N_ROWS + sb * 64 + wc * 32 + lane;
        dst[0]  = cs0;                 // n=0 cols
        dst[16] = cs1;                 // n=1 cols
      }
    }

    const bool last = (t + 1 == t1);
    const bool swi  = (t + 1 == n1) && !last;
    if (last || swi) {                 // flush row sums (atomic: wc=0 + wc=1)
#pragma unroll
      for (int i = 0; i < 16; ++i) {
        float v = rs[i];
        v += __shfl_xor(v, 1, 64);
        v += __shfl_xor(v, 2, 64);
        v += __shfl_xor(v, 4, 64);
        v += __shfl_xor(v, 8, 64);
        rs[i] = v;
      }
      if (l15 == 0) {
        const int g = lane >> 4;
#pragma unroll
        for (int i = 0; i < 16; ++i)
          atomicAdd(&prow[(size_t)k * N_ROWS + rb * 128 + wr * 64 +
                          (i >> 2) * 16 + g * 4 + (i & 3)], rs[i]);
      }
#pragma unroll
      for (int i = 0; i < 16; ++i) rs[i] = 0.f;
    }
    if (swi) {                         // switch to strip B: reload A slice
      rb = p;
      load_af(gb, rb, wr, l15, q8, af);
    }
    __syncthreads();                   // buf(t+1) resident; buf(t) reads done
  }
}

// ------------- kernel 3a: per-64-row loss partials (4-way slot split) ------
__global__ __launch_bounds__(256) void nt_finalize1(
    const float* __restrict__ prow, const float* __restrict__ pcol,
    const float* __restrict__ picked_cross, float* __restrict__ loss_part) {
  const int blk = blockIdx.x, tid = threadIdx.x;   // 128 blocks x 256 thr
  const int pan = blk >> 1;                        // 128-row panel
  const int l   = tid & 63;
  const int r   = pan * 128 + (blk & 1) * 64 + l;
  const int g   = tid >> 6;                        // 4 slot groups
  float s = 0.f;
  if (g == 0) {
#pragma unroll
    for (int j = 0; j < NSPLIT; ++j) s += prow[(size_t)j * N_ROWS + r];
  } else {
    for (int rb = pan + g; rb < NPANEL; rb += 3) {   // rb = pan+1..63, 3-way
      s += pcol[(size_t)(2 * rb) * N_ROWS + r];
      s += pcol[(size_t)(2 * rb + 1) * N_ROWS + r];
    }
  }
  __shared__ float red[4][64];
  red[g][l] = s;
  __syncthreads();
  if (g == 0) {
    float tot = red[0][l] + red[1][l] + red[2][l] + red[3][l];
    const float pick = (r < B_ROWS) ? 2.0f : picked_cross[r - B_ROWS];
    float local = __logf(tot) - pick;
#pragma unroll
    for (int m = 1; m < 64; m <<= 1) local += __shfl_xor(local, m, 64);
    if (l == 0) loss_part[blk] = local;
  }
}

// ------------- kernel 3b: final mean ---------------------------------------
__global__ __launch_bounds__(128) void nt_finalize2(
    const float* __restrict__ loss_part, float* __restrict__ out) {
  const int tid = threadIdx.x;
  float v = loss_part[tid];
#pragma unroll
  for (int m = 1; m < 64; m <<= 1) v += __shfl_xor(v, m, 64);
  __shared__ float red[2];
  if ((tid & 63) == 0) red[tid >> 6] = v;
  __syncthreads();
  if (tid == 0) out[0] = (red[0] + red[1]) / (float)N_ROWS;
}

// ---------------------------------------------------------------------------
extern "C" void kernel_launch(void* const* d_in, const int* in_sizes, int n_in,
                              void* d_out, int out_size, void* d_ws, size_t ws_size,
                              hipStream_t stream) {
  const float* f1 = (const float*)d_in[0];
  const float* f2 = (const float*)d_in[1];
  float* out = (float*)d_out;

  char* ws = (char*)d_ws;
  unsigned char* G    = (unsigned char*)ws;                          // 2 MB fp8
  float* prow         = (float*)(ws + (size_t)2 * 1024 * 1024);      // 1 MB
  float* pcol         = (float*)(ws + (size_t)3 * 1024 * 1024);      // 4 MB
  float* picked_cross = (float*)(ws + (size_t)7 * 1024 * 1024);      // 16 KB
  float* loss_part    = (float*)(ws + (size_t)7 * 1024 * 1024 + 64 * 1024);

  hipLaunchKernelGGL(nt_norm_picked, dim3(B_ROWS / 2), dim3(256), 0, stream,
                     f1, f2, G, picked_cross, prow);
  hipLaunchKernelGGL(nt_gemm_tri, dim3(1024), dim3(256), 0, stream,
                     G, prow, pcol);
  hipLaunchKernelGGL(nt_finalize1, dim3(128), dim3(256), 0, stream,
                     prow, pcol, picked_cross, loss_part);
  hipLaunchKernelGGL(nt_finalize2, dim3(1), dim3(128), 0, stream,
                     loss_part, out);
}

// Round 9
// 54.264 us; speedup vs baseline: 1.5201x; 1.5201x over previous
//
#include <hip/hip_runtime.h>
#include <hip/hip_bf16.h>
#include <math.h>

// ---------------------------------------------------------------------------
// NTXentLoss fused, symmetric triangle, fp8(e4m3) GEMM, spill-free geometry.
// loss = mean(lse(logits) - picked), logits = G G^T, G = sqrt(2)*f/||f|| fp8.
// R8 post-mortem: wave tile 64x32 needed ~131 VGPR > 128 cap of (256,4) ->
// scratch spill (97 MB writes). Fix: wave tile 32x64 (af[2][8]=32 regs,
// acc[2][4]=32, rs[8]) ~100 regs, no spill. Staging model: global_load_lds
// drains ~16 B/cyc/CU -> fp8 16 KB subtile ~1024 cyc < MFMA 1242 cyc.
// 1024 blocks = 32 strip-pairs x 32 splits, XCD-grouped, 4 blocks/CU.
// prow: plain stores (wave owns full rows; unique (k,row) writer), zero-init
// in norm kernel. pcol[4rb+wid]: writer-unique. picked[i<B]=2 exactly.
// ---------------------------------------------------------------------------

#define B_ROWS 4096
#define D_DIM  256
#define N_ROWS 8192
#define NPANEL 64
#define NSPLIT 32

typedef __attribute__((ext_vector_type(4))) float f32x4;

// ---------------- kernel 1: normalize (fp32 -> fp8) + picked ---------------
__global__ __launch_bounds__(256) void nt_norm_picked(
    const float* __restrict__ f1, const float* __restrict__ f2,
    unsigned char* __restrict__ G, float* __restrict__ picked_cross,
    float* __restrict__ prow) {
  __shared__ float4 vbuf[2][64];
  __shared__ float ssbuf[2];
  const int tid = threadIdx.x, lane = tid & 63, w = tid >> 6;
  // zero prow: 32*8192 floats = 65536 float4 (grid 2048 covers)
  const int zidx = blockIdx.x * 256 + tid;
  if (zidx < 65536) reinterpret_cast<float4*>(prow)[zidx] = float4{0.f, 0.f, 0.f, 0.f};
  const int pl = w >> 1, src = w & 1;
  const int p = blockIdx.x * 2 + pl;               // pair index 0..B-1
  const float* rowp = (src == 0 ? f1 : f2) + (size_t)p * D_DIM;
  float4 v = reinterpret_cast<const float4*>(rowp)[lane];
  float ss = v.x * v.x + v.y * v.y + v.z * v.z + v.w * v.w;
#pragma unroll
  for (int m = 1; m < 64; m <<= 1) ss += __shfl_xor(ss, m, 64);
  const float scale = 1.41421356237309515f * rsqrtf(fmaxf(ss, 1e-30f));
  int wpk = __builtin_amdgcn_cvt_pk_fp8_f32(v.x * scale, v.y * scale, 0, false);
  wpk     = __builtin_amdgcn_cvt_pk_fp8_f32(v.z * scale, v.w * scale, wpk, true);
  const int grow = p + src * B_ROWS;
  reinterpret_cast<int*>(G + (size_t)grow * D_DIM)[lane] = wpk;
  if (src == 0) { vbuf[pl][lane] = v; if (lane == 0) ssbuf[pl] = ss; }
  __syncthreads();
  if (src == 1) {
    float4 u = vbuf[pl][lane];
    float d = v.x * u.x + v.y * u.y + v.z * u.z + v.w * u.w;
#pragma unroll
    for (int m = 1; m < 64; m <<= 1) d += __shfl_xor(d, m, 64);
    if (lane == 0)
      picked_cross[p] = 2.0f * d * rsqrtf(ss) * rsqrtf(ssbuf[pl]);
  }
}

// ------------- staging: 16KB contiguous global -> LDS, swizzled ------------
// LDS[o] = G[base + swz(o)], swz(o) = o ^ (((o>>8)&7)<<4)  (256B fp8 rows).
__device__ __forceinline__ void stage_lds(const char* gsrc_base, char* lds_base,
                                          int tid) {
  const int lane = tid & 63, wid = tid >> 6;
#pragma unroll
  for (int r = 0; r < 4; ++r) {
    const int o  = r * 4096 + wid * 1024 + lane * 16;
    const int so = o ^ (((o >> 8) & 7) << 4);
    __builtin_amdgcn_global_load_lds(
        (const __attribute__((address_space(1))) void*)(gsrc_base + so),
        (__attribute__((address_space(3))) void*)(lds_base + r * 4096 + wid * 1024),
        16, 0, 0);
  }
}

// ---------------- A-slice loader: 32 rows x K=256 fp8 -> 32 VGPR -----------
__device__ __forceinline__ void load_af(const char* gb, int rb, int wid,
                                        int l15, int q8, long af[2][8]) {
#pragma unroll
  for (int m = 0; m < 2; ++m) {
    const int ro = (rb * 128 + wid * 32 + m * 16 + l15) * 256;
#pragma unroll
    for (int ks = 0; ks < 8; ++ks)
      af[m][ks] = *reinterpret_cast<const long*>(gb + ro + ks * 32 + q8);
  }
}

// -------- kernel 2: strip-pair fp8 GEMM, wave tile 32x64, fused exp --------
__global__ __launch_bounds__(256, 4) void nt_gemm_tri(
    const unsigned char* __restrict__ G,
    float* __restrict__ prow,   // [NSPLIT][N_ROWS], zero-init'd, plain stores
    float* __restrict__ pcol)   // [4*NPANEL][N_ROWS], writer-covered
{
  // XCD-grouped remap: 1024 blocks -> 128 consecutive work items per XCD.
  const int wg  = (blockIdx.x & 7) * 128 + (blockIdx.x >> 3);
  const int p   = wg >> 5;             // pair 0..31: strips rbA=63-p, rbB=p
  const int k   = wg & 31;             // split 0..31
  const int rbA = 63 - p;
  const int n1  = 2 * (rbA + 1);       // subtiles in strip A
  const int t0  = (130 * k) >> 5;
  const int t1  = (130 * (k + 1)) >> 5;

  const int tid = threadIdx.x, lane = tid & 63, wid = tid >> 6;
  const int l15 = lane & 15, q8 = (lane >> 4) << 3;

  __shared__ long ldsq[4096];          // 32 KB = 2 x 16 KB B buffers
  char* ldsb = reinterpret_cast<char*>(ldsq);
  const char* gb = reinterpret_cast<const char*>(G);

  int rb = (t0 < n1) ? rbA : p;
  stage_lds(gb + (size_t)(t0 < n1 ? t0 : t0 - n1) * 16384, ldsb, tid);

  long af[2][8];                       // 32 rows x K=256 fp8 slice
  load_af(gb, rb, wid, l15, q8, af);

  float rs[8];
#pragma unroll
  for (int i = 0; i < 8; ++i) rs[i] = 0.f;
  __syncthreads();

  for (int t = t0; t < t1; ++t) {
    char* bbuf = ldsb + ((t - t0) & 1) * 16384;
    if (t + 1 < t1) {
      const int sbn = (t + 1 < n1) ? t + 1 : t + 1 - n1;
      stage_lds(gb + (size_t)sbn * 16384, ldsb + ((t + 1 - t0) & 1) * 16384, tid);
    }
    const int sb = (t < n1) ? t : t - n1;

    f32x4 acc[2][4] = {};
#pragma unroll
    for (int ks = 0; ks < 8; ++ks) {
      long bf[4];
#pragma unroll
      for (int n = 0; n < 4; ++n) {
        const int brow = n * 16 + l15;
        const int off  = (brow * 256 + ks * 32 + q8) ^ ((brow & 7) << 4);
        bf[n] = *reinterpret_cast<const long*>(bbuf + off);
      }
#pragma unroll
      for (int m = 0; m < 2; ++m)
#pragma unroll
        for (int n = 0; n < 4; ++n)
          acc[m][n] = __builtin_amdgcn_mfma_f32_16x16x32_fp8_fp8(
              af[m][ks], bf[n], acc[m][n], 0, 0, 0);
    }

    // exp + sums. acc row = wid*32+m*16+(lane>>4)*4+j, col = sb*64+n*16+l15.
    float cs[4] = {0.f, 0.f, 0.f, 0.f};
#pragma unroll
    for (int m = 0; m < 2; ++m)
#pragma unroll
      for (int n = 0; n < 4; ++n)
#pragma unroll
        for (int j = 0; j < 4; ++j) {
          const float e = __expf(acc[m][n][j]);
          rs[m * 4 + j] += e;
          cs[n] += e;
        }
    if ((sb >> 1) != rb) {             // off-diagonal: store col sums
#pragma unroll
      for (int n = 0; n < 4; ++n) {
        float c = cs[n];
        c += __shfl_xor(c, 16, 64);
        c += __shfl_xor(c, 32, 64);
        if (lane < 16)
          pcol[(size_t)(4 * rb + wid) * N_ROWS + sb * 64 + n * 16 + lane] = c;
      }
    }

    const bool last = (t + 1 == t1);
    const bool swi  = (t + 1 == n1) && !last;
    if (last || swi) {                 // flush row sums (plain: wave owns rows)
#pragma unroll
      for (int i = 0; i < 8; ++i) {
        float v = rs[i];
        v += __shfl_xor(v, 1, 64);
        v += __shfl_xor(v, 2, 64);
        v += __shfl_xor(v, 4, 64);
        v += __shfl_xor(v, 8, 64);
        rs[i] = v;
      }
      if (l15 == 0) {
        const int g = lane >> 4;
#pragma unroll
        for (int i = 0; i < 8; ++i)
          prow[(size_t)k * N_ROWS + rb * 128 + wid * 32 +
               (i >> 2) * 16 + g * 4 + (i & 3)] = rs[i];
      }
#pragma unroll
      for (int i = 0; i < 8; ++i) rs[i] = 0.f;
    }
    if (swi) {                         // switch to strip B: reload A slice
      rb = p;
      load_af(gb, rb, wid, l15, q8, af);
    }
    __syncthreads();                   // buf(t+1) resident; buf(t) reads done
  }
}

// ------------- kernel 3a: per-64-row loss partials (4-way slot split) ------
__global__ __launch_bounds__(256) void nt_finalize1(
    const float* __restrict__ prow, const float* __restrict__ pcol,
    const float* __restrict__ picked_cross, float* __restrict__ loss_part) {
  const int blk = blockIdx.x, tid = threadIdx.x;   // 128 blocks x 256 thr
  const int pan = blk >> 1;                        // 128-row panel
  const int l   = tid & 63;
  const int r   = pan * 128 + (blk & 1) * 64 + l;
  const int g   = tid >> 6;                        // 4 slot groups
  float s = 0.f;
  if (g == 0) {
#pragma unroll
    for (int j = 0; j < NSPLIT; ++j) s += prow[(size_t)j * N_ROWS + r];
  } else {
    for (int rb = pan + g; rb < NPANEL; rb += 3) {   // rb = pan+1..63, 3-way
      const float* b = pcol + (size_t)(4 * rb) * N_ROWS + r;
      s += b[0] + b[(size_t)N_ROWS] + b[(size_t)2 * N_ROWS] + b[(size_t)3 * N_ROWS];
    }
  }
  __shared__ float red[4][64];
  red[g][l] = s;
  __syncthreads();
  if (g == 0) {
    float tot = red[0][l] + red[1][l] + red[2][l] + red[3][l];
    const float pick = (r < B_ROWS) ? 2.0f : picked_cross[r - B_ROWS];
    float local = __logf(tot) - pick;
#pragma unroll
    for (int m = 1; m < 64; m <<= 1) local += __shfl_xor(local, m, 64);
    if (l == 0) loss_part[blk] = local;
  }
}

// ------------- kernel 3b: final mean ---------------------------------------
__global__ __launch_bounds__(128) void nt_finalize2(
    const float* __restrict__ loss_part, float* __restrict__ out) {
  const int tid = threadIdx.x;
  float v = loss_part[tid];
#pragma unroll
  for (int m = 1; m < 64; m <<= 1) v += __shfl_xor(v, m, 64);
  __shared__ float red[2];
  if ((tid & 63) == 0) red[tid >> 6] = v;
  __syncthreads();
  if (tid == 0) out[0] = (red[0] + red[1]) / (float)N_ROWS;
}

// ---------------------------------------------------------------------------
extern "C" void kernel_launch(void* const* d_in, const int* in_sizes, int n_in,
                              void* d_out, int out_size, void* d_ws, size_t ws_size,
                              hipStream_t stream) {
  const float* f1 = (const float*)d_in[0];
  const float* f2 = (const float*)d_in[1];
  float* out = (float*)d_out;

  char* ws = (char*)d_ws;
  unsigned char* G    = (unsigned char*)ws;                          // 2 MB fp8
  float* prow         = (float*)(ws + (size_t)2 * 1024 * 1024);      // 1 MB
  float* pcol         = (float*)(ws + (size_t)3 * 1024 * 1024);      // 8 MB
  float* picked_cross = (float*)(ws + (size_t)11 * 1024 * 1024);     // 16 KB
  float* loss_part    = (float*)(ws + (size_t)11 * 1024 * 1024 + 64 * 1024);

  hipLaunchKernelGGL(nt_norm_picked, dim3(B_ROWS / 2), dim3(256), 0, stream,
                     f1, f2, G, picked_cross, prow);
  hipLaunchKernelGGL(nt_gemm_tri, dim3(1024), dim3(256), 0, stream,
                     G, prow, pcol);
  hipLaunchKernelGGL(nt_finalize1, dim3(128), dim3(256), 0, stream,
                     prow, pcol, picked_cross, loss_part);
  hipLaunchKernelGGL(nt_finalize2, dim3(1), dim3(128), 0, stream,
                     loss_part, out);
}